// Round 2
// baseline (763.306 us; speedup 1.0000x reference)
//
#include <hip/hip_runtime.h>

#define SEQ 8192
#define DIM 768

typedef __attribute__((ext_vector_type(8))) short s16x8;   // 8 x bf16
typedef __attribute__((ext_vector_type(4))) float f32x4;

// RNE float -> bf16
__device__ __forceinline__ unsigned short f2bf(float f) {
  union { float f; unsigned u; } v; v.f = f;
  unsigned r = v.u + 0x7FFFu + ((v.u >> 16) & 1u);
  return (unsigned short)(r >> 16);
}

__device__ __forceinline__ float bf2f(unsigned short s) {
  union { unsigned u; float f; } v; v.u = ((unsigned)s) << 16;
  return v.f;
}

// async global->LDS 16B copy (used by proj kernel only)
__device__ __forceinline__ void gll16(const void* gsrc, void* ldst) {
  __builtin_amdgcn_global_load_lds(
      (__attribute__((address_space(1))) unsigned int*)gsrc,
      (__attribute__((address_space(3))) unsigned int*)ldst, 16, 0, 0);
}

// ---------------- fused cast kernel: x (6144 blocks) + wq/wk/wv (576 each) ----------------
#define XN4 (SEQ * DIM / 4)     // 1572864
#define WN4 (DIM * DIM / 4)     // 147456

__global__ void cast_all_kernel(const float* __restrict__ x, const float* __restrict__ wq,
                                const float* __restrict__ wk, const float* __restrict__ wv,
                                unsigned short* __restrict__ dx, unsigned short* __restrict__ dq,
                                unsigned short* __restrict__ dk, unsigned short* __restrict__ dv) {
  int i = blockIdx.x * blockDim.x + threadIdx.x;
  const float* s;
  unsigned short* d;
  int off;
  if (i < XN4) {
    s = x; d = dx; off = i;
  } else {
    int j = i - XN4;
    int wi = j / WN4;
    off = j - wi * WN4;
    s = (wi == 0) ? wq : ((wi == 1) ? wk : wv);
    d = (wi == 0) ? dq : ((wi == 1) ? dk : dv);
  }
  float4 v = ((const float4*)s)[off];
  ushort4 r; r.x = f2bf(v.x); r.y = f2bf(v.y); r.z = f2bf(v.z); r.w = f2bf(v.w);
  ((ushort4*)d)[off] = r;
}

// ---------------- projection GEMM: C[m][n] = sum_k X[m][k]*W[n][k] ----------------
__global__ __launch_bounds__(256, 2)
void proj_kernel(const unsigned short* __restrict__ X,
                 const unsigned short* __restrict__ Wq,
                 const unsigned short* __restrict__ Wk,
                 const unsigned short* __restrict__ Wv,
                 unsigned short* __restrict__ Qb,
                 unsigned short* __restrict__ Kb,
                 unsigned short* __restrict__ Vtb) {
  __shared__ __align__(16) char lds[65536];
  const int tid = threadIdx.x;
  const int lane = tid & 63, wv = tid >> 6;
  const int l15 = lane & 15, l4 = lane >> 4;
  const int mt = blockIdx.x, nt = blockIdx.y, z = blockIdx.z;
  const unsigned short* W = (z == 0) ? Wq : ((z == 1) ? Wk : Wv);

  f32x4 acc[4][4];
#pragma unroll
  for (int i = 0; i < 4; ++i)
#pragma unroll
    for (int j = 0; j < 4; ++j) acc[i][j] = f32x4{0.f, 0.f, 0.f, 0.f};

  auto stage = [&](int kk) {
    char* At = lds + (kk & 1) * 32768;
    char* Bt = At + 16384;
    const int d0 = kk * 64;
#pragma unroll
    for (int i = 0; i < 4; ++i) {
      int s = i * 256 + tid;
      int row = s >> 3, c = (s & 7) ^ (row & 7);
      gll16(X + (long)(mt * 128 + row) * DIM + d0 + c * 8, At + i * 4096 + (wv << 10));
      gll16(W + (long)(nt * 128 + row) * DIM + d0 + c * 8, Bt + i * 4096 + (wv << 10));
    }
  };

  stage(0);
#pragma unroll 1
  for (int kk = 0; kk < 12; ++kk) {
    __syncthreads();
    if (kk + 1 < 12) stage(kk + 1);
    const char* At = lds + (kk & 1) * 32768;
    const char* Bt = At + 16384;
#pragma unroll
    for (int ks = 0; ks < 2; ++ks) {
      const int c = ks * 4 + l4;
      s16x8 a[4], b[4];
#pragma unroll
      for (int mi = 0; mi < 4; ++mi) {
        int row = (wv & 1) * 64 + mi * 16 + l15;
        a[mi] = *(const s16x8*)(At + row * 128 + ((c ^ (row & 7)) << 4));
      }
#pragma unroll
      for (int ni = 0; ni < 4; ++ni) {
        int row = (wv >> 1) * 64 + ni * 16 + l15;
        b[ni] = *(const s16x8*)(Bt + row * 128 + ((c ^ (row & 7)) << 4));
      }
#pragma unroll
      for (int mi = 0; mi < 4; ++mi)
#pragma unroll
        for (int ni = 0; ni < 4; ++ni)
          acc[mi][ni] = __builtin_amdgcn_mfma_f32_16x16x32_bf16(a[mi], b[ni], acc[mi][ni], 0, 0, 0);
    }
  }

#pragma unroll
  for (int mi = 0; mi < 4; ++mi)
#pragma unroll
    for (int ni = 0; ni < 4; ++ni) {
      int row0 = mt * 128 + (wv & 1) * 64 + mi * 16 + l4 * 4;
      int col = nt * 128 + (wv >> 1) * 64 + ni * 16 + l15;
      if (z == 2) {
        ushort4 r;
        r.x = f2bf(acc[mi][ni][0]); r.y = f2bf(acc[mi][ni][1]);
        r.z = f2bf(acc[mi][ni][2]); r.w = f2bf(acc[mi][ni][3]);
        *(ushort4*)(Vtb + (long)col * SEQ + row0) = r;  // V transposed: Vt[col][row]
      } else {
        unsigned short* dst = (z == 0) ? Qb : Kb;
#pragma unroll
        for (int g = 0; g < 4; ++g)
          dst[(long)(row0 + g) * DIM + col] = f2bf(acc[mi][ni][g]);
      }
    }
}

// ---------------- flash attention: direct global->reg fragments (no staging LDS) ----
// BM=64 q rows/block, BN=256 keys/iter, 8 waves. Q/K/V MFMA fragments are loaded
// straight from global (16B/lane coalesced dwordx4); L1/L2 serve the re-reads
// (Qx4, Kx2, Vx1). Only P goes through LDS (shared across waves). 2 barriers/iter.
#define SCALE_LOG2E 0.05205878f  // (1/sqrt(768)) * log2(e)

__global__ __launch_bounds__(512, 2)
void flash_kernel(const unsigned short* __restrict__ Q,   // [8192][768] bf16
                  const unsigned short* __restrict__ K,   // [8192][768] bf16
                  const unsigned short* __restrict__ V,   // [768][8192] bf16 (transposed)
                  unsigned short* __restrict__ partp,     // [G][8192][768] bf16 (G-split mode)
                  float* __restrict__ outf,               // [8192][768] fp32 (norm mode)
                  float* __restrict__ lout,               // [G][8192] (G-split mode)
                  int kv_len, int norm_out) {
  // LDS: P 32KB (swizzled [64][256] bf16) + l 1KB
  __shared__ __align__(16) char lds[32768 + 1024];
  char* Pl = lds;
  float* l_part = (float*)(lds + 32768);  // [4][64]

  const int tid = threadIdx.x;
  const int lane = tid & 63, wv = tid >> 6;
  const int l15 = lane & 15, l4 = lane >> 4;
  const int qtile = blockIdx.x, split = blockIdx.y;
  const long kv0 = (long)split * kv_len;
  const long qrow0 = (long)qtile * 64;
  const int R = wv & 1;   // S row-half
  const int C = wv >> 1;  // S key-quarter

  f32x4 acc_o[4][6];
  float acc_lp[8];
#pragma unroll
  for (int i = 0; i < 4; ++i)
#pragma unroll
    for (int j = 0; j < 6; ++j) acc_o[i][j] = f32x4{0.f, 0.f, 0.f, 0.f};
#pragma unroll
  for (int i = 0; i < 8; ++i) acc_lp[i] = 0.f;

  const int niter = kv_len >> 8;

  // iter-invariant fragment base addresses (per-lane)
  const unsigned short* Qrow[2];
#pragma unroll
  for (int rt = 0; rt < 2; ++rt)
    Qrow[rt] = Q + (qrow0 + R * 32 + rt * 16 + l15) * (long)DIM;
  const unsigned short* Vrow[2];
#pragma unroll
  for (int t = 0; t < 2; ++t)
    Vrow[t] = V + (long)((wv + 8 * t) * 16 + l15) * SEQ;

#pragma unroll 1
  for (int it = 0; it < niter; ++it) {
    const long kb = kv0 + (long)it * 256;

    // ---- QK: S[64x256]; per-wave region [32 rows x 64 keys]; frags from global ----
    f32x4 acc_s[2][4];
#pragma unroll
    for (int a = 0; a < 2; ++a)
#pragma unroll
      for (int b = 0; b < 4; ++b) acc_s[a][b] = f32x4{0.f, 0.f, 0.f, 0.f};

    const unsigned short* Kbase = K + (kb + C * 64 + l15) * (long)DIM;

#pragma unroll 2
    for (int r = 0; r < 12; ++r) {
#pragma unroll
      for (int ks = 0; ks < 2; ++ks) {
        const int dc = r * 64 + (ks * 4 + l4) * 8;
        s16x8 af[2], bk[4];
#pragma unroll
        for (int rt = 0; rt < 2; ++rt)
          af[rt] = *(const s16x8*)(Qrow[rt] + dc);
#pragma unroll
        for (int ct = 0; ct < 4; ++ct)
          bk[ct] = *(const s16x8*)(Kbase + (long)ct * 16 * DIM + dc);
#pragma unroll
        for (int rt = 0; rt < 2; ++rt)
#pragma unroll
          for (int ct = 0; ct < 4; ++ct)
            acc_s[rt][ct] = __builtin_amdgcn_mfma_f32_16x16x32_bf16(af[rt], bk[ct], acc_s[rt][ct], 0, 0, 0);
      }
    }

    // ---- P = exp(S/sqrt(D)) -> bf16 -> LDS (swizzled [64][256]); per-lane l partials ----
#pragma unroll
    for (int rt = 0; rt < 2; ++rt)
#pragma unroll
      for (int ct = 0; ct < 4; ++ct)
#pragma unroll
        for (int g = 0; g < 4; ++g) {
          float p = exp2f(acc_s[rt][ct][g] * SCALE_LOG2E);
          acc_lp[rt * 4 + g] += p;
          int row = R * 32 + rt * 16 + l4 * 4 + g;
          int col = C * 64 + ct * 16 + l15;
          int off = row * 512 + ((((col >> 3) ^ (row & 7))) << 4) + ((col & 7) << 1);
          *(unsigned short*)(Pl + off) = f2bf(p);
        }
    __syncthreads();  // P visible to all waves

    // ---- PV: O[64x768] += P[64x256] @ V; pa from LDS, vb from global ----
#pragma unroll
    for (int cc = 0; cc < 3; ++cc) {
#pragma unroll 2
      for (int kh = 0; kh < 4; ++kh) {
#pragma unroll
        for (int ks = 0; ks < 2; ++ks) {
          s16x8 pa[4], vb[2];
          const int ck = kh * 8 + ks * 4 + l4;
#pragma unroll
          for (int rs = 0; rs < 4; ++rs) {
            int row = rs * 16 + l15;
            int pc = (ck & ~7) | ((ck & 7) ^ (row & 7));
            pa[rs] = *(const s16x8*)(Pl + row * 512 + (pc << 4));
          }
          const long kcol = kb + kh * 64 + (ks * 4 + l4) * 8;
#pragma unroll
          for (int t = 0; t < 2; ++t)
            vb[t] = *(const s16x8*)(Vrow[t] + (long)cc * 256 * SEQ + kcol);
#pragma unroll
          for (int rs = 0; rs < 4; ++rs)
#pragma unroll
            for (int t = 0; t < 2; ++t)
              acc_o[rs][cc * 2 + t] =
                  __builtin_amdgcn_mfma_f32_16x16x32_bf16(pa[rs], vb[t], acc_o[rs][cc * 2 + t], 0, 0, 0);
        }
      }
    }
    __syncthreads();  // P consumed before next iter's P writes
  }

  // ---- l reduction: butterfly over lane bits 0..3 (16 cols/group), combine quarters ----
#pragma unroll
  for (int i = 0; i < 8; ++i) {
    float v = acc_lp[i];
    v += __shfl_xor(v, 1); v += __shfl_xor(v, 2);
    v += __shfl_xor(v, 4); v += __shfl_xor(v, 8);
    acc_lp[i] = v;
  }
  if (l15 == 0) {
#pragma unroll
    for (int rt = 0; rt < 2; ++rt)
#pragma unroll
      for (int g = 0; g < 4; ++g)
        l_part[C * 64 + R * 32 + rt * 16 + l4 * 4 + g] = acc_lp[rt * 4 + g];
  }
  __syncthreads();

  if (!norm_out) {
    if (tid < 64)
      lout[(long)split * SEQ + qrow0 + tid] =
          l_part[tid] + l_part[64 + tid] + l_part[128 + tid] + l_part[192 + tid];
#pragma unroll
    for (int rt = 0; rt < 4; ++rt) {
      int row = rt * 16 + l4 * 4;
#pragma unroll
      for (int j = 0; j < 6; ++j) {
        int cc = j >> 1, t = j & 1;
        int col = (cc * 16 + wv + 8 * t) * 16 + l15;
#pragma unroll
        for (int g = 0; g < 4; ++g)
          partp[(long)split * SEQ * DIM + (qrow0 + row + g) * DIM + col] = f2bf(acc_o[rt][j][g]);
      }
    }
  } else {
    float linv[4][4];
#pragma unroll
    for (int rt = 0; rt < 4; ++rt)
#pragma unroll
      for (int g = 0; g < 4; ++g) {
        int row = rt * 16 + l4 * 4 + g;
        linv[rt][g] = 1.0f / (l_part[row] + l_part[64 + row] + l_part[128 + row] + l_part[192 + row]);
      }
#pragma unroll
    for (int rt = 0; rt < 4; ++rt) {
      int row = rt * 16 + l4 * 4;
#pragma unroll
      for (int j = 0; j < 6; ++j) {
        int cc = j >> 1, t = j & 1;
        int col = (cc * 16 + wv + 8 * t) * 16 + l15;
#pragma unroll
        for (int g = 0; g < 4; ++g)
          outf[(qrow0 + row + g) * DIM + col] = acc_o[rt][j][g] * linv[rt][g];
      }
    }
  }
}

// ---------------- combine (G=2): out = (p0+p1)/(l0+l1), partials bf16 ----------------
__global__ void combine_kernel(const unsigned short* __restrict__ part,
                               const float* __restrict__ lsum,
                               float* __restrict__ out, int n4) {
  int i = blockIdx.x * blockDim.x + threadIdx.x;
  if (i >= n4) return;
  int row = (i * 4) / DIM;
  ushort4 p0 = ((const ushort4*)part)[i];
  ushort4 p1 = ((const ushort4*)(part + (long)SEQ * DIM))[i];
  float inv = 1.0f / (lsum[row] + lsum[SEQ + row]);
  float4 o;
  o.x = (bf2f(p0.x) + bf2f(p1.x)) * inv;
  o.y = (bf2f(p0.y) + bf2f(p1.y)) * inv;
  o.z = (bf2f(p0.z) + bf2f(p1.z)) * inv;
  o.w = (bf2f(p0.w) + bf2f(p1.w)) * inv;
  ((float4*)out)[i] = o;
}

// ---------------- host ----------------
extern "C" void kernel_launch(void* const* d_in, const int* in_sizes, int n_in,
                              void* d_out, int out_size, void* d_ws, size_t ws_size,
                              hipStream_t stream) {
  const float* x = (const float*)d_in[0];
  const float* wq = (const float*)d_in[1];
  const float* wk = (const float*)d_in[2];
  const float* wv = (const float*)d_in[3];
  float* out = (float*)d_out;
  char* ws = (char*)d_ws;

  const size_t o_xbf = 0;
  const size_t o_wq = o_xbf + (size_t)SEQ * DIM * 2;
  const size_t o_wk = o_wq + (size_t)DIM * DIM * 2;
  const size_t o_wv = o_wk + (size_t)DIM * DIM * 2;
  const size_t o_q = o_wv + (size_t)DIM * DIM * 2;
  const size_t o_k = o_q + (size_t)SEQ * DIM * 2;
  const size_t o_vt = o_k + (size_t)SEQ * DIM * 2;
  const size_t o_part = o_vt + (size_t)SEQ * DIM * 2;
  const size_t o_l = o_part + (size_t)2 * SEQ * DIM * 2;   // bf16 partials
  const size_t total_g2 = o_l + (size_t)2 * SEQ * 4;

  unsigned short* Xbf = (unsigned short*)(ws + o_xbf);
  unsigned short* Wqb = (unsigned short*)(ws + o_wq);
  unsigned short* Wkb = (unsigned short*)(ws + o_wk);
  unsigned short* Wvb = (unsigned short*)(ws + o_wv);
  unsigned short* Qb = (unsigned short*)(ws + o_q);
  unsigned short* Kb = (unsigned short*)(ws + o_k);
  unsigned short* Vtb = (unsigned short*)(ws + o_vt);
  unsigned short* part = (unsigned short*)(ws + o_part);
  float* lbuf = (float*)(ws + o_l);

  const int G = (ws_size >= total_g2) ? 2 : 1;

  cast_all_kernel<<<7872, 256, 0, stream>>>(x, wq, wk, wv, Xbf, Wqb, Wkb, Wvb);
  proj_kernel<<<dim3(64, 6, 3), 256, 0, stream>>>(Xbf, Wqb, Wkb, Wvb, Qb, Kb, Vtb);
  if (G == 2) {
    flash_kernel<<<dim3(128, 2), 512, 0, stream>>>(Qb, Kb, Vtb, part, nullptr, lbuf, SEQ / 2, 0);
    combine_kernel<<<6144, 256, 0, stream>>>(part, lbuf, out, SEQ * DIM / 4);
  } else {
    flash_kernel<<<dim3(128, 1), 512, 0, stream>>>(Qb, Kb, Vtb, nullptr, out, nullptr, SEQ, 1);
  }
}

// Round 3
// 366.017 us; speedup vs baseline: 2.0854x; 2.0854x over previous
//
#include <hip/hip_runtime.h>

#define SEQ 8192
#define DIM 768

typedef __attribute__((ext_vector_type(8))) short s16x8;   // 8 x bf16
typedef __attribute__((ext_vector_type(4))) float f32x4;
typedef __attribute__((ext_vector_type(16))) float f32x16;

// RNE float -> bf16
__device__ __forceinline__ unsigned short f2bf(float f) {
  union { float f; unsigned u; } v; v.f = f;
  unsigned r = v.u + 0x7FFFu + ((v.u >> 16) & 1u);
  return (unsigned short)(r >> 16);
}

__device__ __forceinline__ float bf2f(unsigned short s) {
  union { unsigned u; float f; } v; v.u = ((unsigned)s) << 16;
  return v.f;
}

// async global->LDS 16B copy: lds dest = wave-uniform base + lane*16
__device__ __forceinline__ void gll16(const void* gsrc, void* ldst) {
  __builtin_amdgcn_global_load_lds(
      (__attribute__((address_space(1))) unsigned int*)gsrc,
      (__attribute__((address_space(3))) unsigned int*)ldst, 16, 0, 0);
}

// ---------------- fused cast kernel: x (6144 blocks) + wq/wk/wv (576 each) ----------------
#define XN4 (SEQ * DIM / 4)     // 1572864
#define WN4 (DIM * DIM / 4)     // 147456

__global__ void cast_all_kernel(const float* __restrict__ x, const float* __restrict__ wq,
                                const float* __restrict__ wk, const float* __restrict__ wv,
                                unsigned short* __restrict__ dx, unsigned short* __restrict__ dq,
                                unsigned short* __restrict__ dk, unsigned short* __restrict__ dv) {
  int i = blockIdx.x * blockDim.x + threadIdx.x;
  const float* s;
  unsigned short* d;
  int off;
  if (i < XN4) {
    s = x; d = dx; off = i;
  } else {
    int j = i - XN4;
    int wi = j / WN4;
    off = j - wi * WN4;
    s = (wi == 0) ? wq : ((wi == 1) ? wk : wv);
    d = (wi == 0) ? dq : ((wi == 1) ? dk : dv);
  }
  float4 v = ((const float4*)s)[off];
  ushort4 r; r.x = f2bf(v.x); r.y = f2bf(v.y); r.z = f2bf(v.z); r.w = f2bf(v.w);
  ((ushort4*)d)[off] = r;
}

// ---------------- projection GEMM: C[m][n] = sum_k X[m][k]*W[n][k] ----------------
__global__ __launch_bounds__(256, 2)
void proj_kernel(const unsigned short* __restrict__ X,
                 const unsigned short* __restrict__ Wq,
                 const unsigned short* __restrict__ Wk,
                 const unsigned short* __restrict__ Wv,
                 unsigned short* __restrict__ Qb,
                 unsigned short* __restrict__ Kb,
                 unsigned short* __restrict__ Vtb) {
  __shared__ __align__(16) char lds[65536];
  const int tid = threadIdx.x;
  const int lane = tid & 63, wv = tid >> 6;
  const int l15 = lane & 15, l4 = lane >> 4;
  const int mt = blockIdx.x, nt = blockIdx.y, z = blockIdx.z;
  const unsigned short* W = (z == 0) ? Wq : ((z == 1) ? Wk : Wv);

  f32x4 acc[4][4];
#pragma unroll
  for (int i = 0; i < 4; ++i)
#pragma unroll
    for (int j = 0; j < 4; ++j) acc[i][j] = f32x4{0.f, 0.f, 0.f, 0.f};

  auto stage = [&](int kk) {
    char* At = lds + (kk & 1) * 32768;
    char* Bt = At + 16384;
    const int d0 = kk * 64;
#pragma unroll
    for (int i = 0; i < 4; ++i) {
      int s = i * 256 + tid;
      int row = s >> 3, c = (s & 7) ^ (row & 7);
      gll16(X + (long)(mt * 128 + row) * DIM + d0 + c * 8, At + i * 4096 + (wv << 10));
      gll16(W + (long)(nt * 128 + row) * DIM + d0 + c * 8, Bt + i * 4096 + (wv << 10));
    }
  };

  stage(0);
#pragma unroll 1
  for (int kk = 0; kk < 12; ++kk) {
    __syncthreads();
    if (kk + 1 < 12) stage(kk + 1);
    const char* At = lds + (kk & 1) * 32768;
    const char* Bt = At + 16384;
#pragma unroll
    for (int ks = 0; ks < 2; ++ks) {
      const int c = ks * 4 + l4;
      s16x8 a[4], b[4];
#pragma unroll
      for (int mi = 0; mi < 4; ++mi) {
        int row = (wv & 1) * 64 + mi * 16 + l15;
        a[mi] = *(const s16x8*)(At + row * 128 + ((c ^ (row & 7)) << 4));
      }
#pragma unroll
      for (int ni = 0; ni < 4; ++ni) {
        int row = (wv >> 1) * 64 + ni * 16 + l15;
        b[ni] = *(const s16x8*)(Bt + row * 128 + ((c ^ (row & 7)) << 4));
      }
#pragma unroll
      for (int mi = 0; mi < 4; ++mi)
#pragma unroll
        for (int ni = 0; ni < 4; ++ni)
          acc[mi][ni] = __builtin_amdgcn_mfma_f32_16x16x32_bf16(a[mi], b[ni], acc[mi][ni], 0, 0, 0);
    }
  }

#pragma unroll
  for (int mi = 0; mi < 4; ++mi)
#pragma unroll
    for (int ni = 0; ni < 4; ++ni) {
      int row0 = mt * 128 + (wv & 1) * 64 + mi * 16 + l4 * 4;
      int col = nt * 128 + (wv >> 1) * 64 + ni * 16 + l15;
      if (z == 2) {
        ushort4 r;
        r.x = f2bf(acc[mi][ni][0]); r.y = f2bf(acc[mi][ni][1]);
        r.z = f2bf(acc[mi][ni][2]); r.w = f2bf(acc[mi][ni][3]);
        *(ushort4*)(Vtb + (long)col * SEQ + row0) = r;  // V transposed: Vt[col][row]
      } else {
        unsigned short* dst = (z == 0) ? Qb : Kb;
#pragma unroll
        for (int g = 0; g < 4; ++g)
          dst[(long)(row0 + g) * DIM + col] = f2bf(acc[mi][ni][g]);
      }
    }
}

// ---------------- flash attention (R0 skeleton + 32x32 PV + full-width V rounds) ----
// BM=64 q rows/block, BN=256 keys/iter, 8 waves.
// QK phase: unchanged from the 293us kernel (16x16x32, [*][64dim] rounds, buffer
//   parity flipped so round 11 reads the LOW buffer).
// PV phase: mfma_32x32x16; V staged [768 vrows][32 keys] per round (48KB x2,
//   XOR-swizzled row-pairs in 128B lines, source pre-swizzled for global_load_lds).
//   All 768 output cols per round -> pa fragments read once (no cc re-read):
//   PV LDS reads 1152 -> 640 per iter.
#define SCALE_LOG2E 0.05205878f  // (1/sqrt(768)) * log2(e)

__global__ __launch_bounds__(512, 2)
void flash_kernel(const unsigned short* __restrict__ Q,   // [8192][768] bf16
                  const unsigned short* __restrict__ K,   // [8192][768] bf16
                  const unsigned short* __restrict__ V,   // [768][8192] bf16 (transposed)
                  unsigned short* __restrict__ partp,     // [G][8192][768] bf16 (G-split mode)
                  float* __restrict__ outf,               // [8192][768] fp32 (norm mode)
                  float* __restrict__ lout,               // [G][8192] (G-split mode)
                  int kv_len, int norm_out) {
  // LDS map: [0..98304) staging arena: QK bufs at 0 / 40960 (40KB each);
  //          PV bufs at 49152 (even v) / 0 (odd v), 48KB each (disjoint pair).
  //          [98304..131072) P (swizzled [64][256] bf16). [131072..132096) l.
  __shared__ __align__(16) char lds[98304 + 32768 + 1024];
  char* Pl = lds + 98304;
  float* l_part = (float*)(lds + 131072);  // [4][64]

  const int tid = threadIdx.x;
  const int lane = tid & 63, wv = tid >> 6;
  const int l15 = lane & 15, l4 = lane >> 4;
  const int l31 = lane & 31, h = lane >> 5;
  const int qtile = blockIdx.x, split = blockIdx.y;
  const long kv0 = (long)split * kv_len;
  const long qrow0 = (long)qtile * 64;
  const int R = wv & 1;   // S row-half
  const int C = wv >> 1;  // S key-quarter

  f32x16 acc_o[2][3];
  float acc_lp[8];
#pragma unroll
  for (int i = 0; i < 2; ++i)
#pragma unroll
    for (int j = 0; j < 3; ++j)
#pragma unroll
      for (int e = 0; e < 16; ++e) acc_o[i][j][e] = 0.f;
#pragma unroll
  for (int i = 0; i < 8; ++i) acc_lp[i] = 0.f;

  const int niter = kv_len >> 8;

#pragma unroll 1
  for (int it = 0; it < niter; ++it) {
    const long kb = kv0 + (long)it * 256;

    auto stageQK = [&](int r) {
      char* Qc = lds + ((r & 1) ^ 1) * 40960;   // parity flipped: round 11 -> low buf
      char* Kc = Qc + 8192;
      const int d0 = r * 64;
      {
        int s = tid;
        int row = s >> 3, c = (s & 7) ^ (row & 7);
        gll16(Q + (qrow0 + row) * DIM + d0 + c * 8, Qc + (wv << 10));
      }
#pragma unroll
      for (int i = 0; i < 4; ++i) {
        int s = i * 512 + tid;
        int row = s >> 3, c = (s & 7) ^ (row & 7);
        gll16(K + (kb + row) * DIM + d0 + c * 8, Kc + i * 8192 + (wv << 10));
      }
    };
    // V round v: [768 vrows][32 keys] bf16, swizzled: data (vr, k8) stored at
    // 16B-slot rp*8 + p3, rp=vr>>1, p3=(((vr&1)<<2)|k8)^(rp&7). Linear dest ->
    // invert swizzle on the global source address (G21).
    auto stagePV = [&](int v) {
      char* Vc = lds + ((v & 1) ^ 1) * 49152;   // even v -> 49152, odd v -> 0
      const long kcol = kb + v * 32;
#pragma unroll
      for (int i = 0; i < 6; ++i) {
        int linear = i * 512 + tid;       // 16B slot index (3072 total)
        int rp = linear >> 3, p3 = linear & 7;
        int orig = p3 ^ (rp & 7);
        int vr = rp * 2 + (orig >> 2);
        int k8 = orig & 3;
        gll16(V + (long)vr * SEQ + kcol + k8 * 8, Vc + i * 8192 + (wv << 10));
      }
    };

    // ---- QK: S[64x256], per-wave region [32 rows x 64 keys] = 2x4 16x16 tiles ----
    f32x4 acc_s[2][4];
#pragma unroll
    for (int a = 0; a < 2; ++a)
#pragma unroll
      for (int b = 0; b < 4; ++b) acc_s[a][b] = f32x4{0.f, 0.f, 0.f, 0.f};

    stageQK(0);
#pragma unroll 1
    for (int r = 0; r < 12; ++r) {
      __syncthreads();  // drains round-r loads; all waves done with round r-1 compute
      if (r + 1 < 12) stageQK(r + 1);
      else stagePV(0);  // pre-issue V round 0 (targets 49152.., disjoint from low QK buf)
      const char* Qc = lds + ((r & 1) ^ 1) * 40960;
      const char* Kc = Qc + 8192;
#pragma unroll
      for (int ks = 0; ks < 2; ++ks) {
        const int c = ks * 4 + l4;
        s16x8 af[2], bk[4];
#pragma unroll
        for (int rt = 0; rt < 2; ++rt) {
          int row = R * 32 + rt * 16 + l15;
          af[rt] = *(const s16x8*)(Qc + row * 128 + ((c ^ (row & 7)) << 4));
        }
#pragma unroll
        for (int ct = 0; ct < 4; ++ct) {
          int kr = C * 64 + ct * 16 + l15;
          bk[ct] = *(const s16x8*)(Kc + kr * 128 + ((c ^ (kr & 7)) << 4));
        }
#pragma unroll
        for (int rt = 0; rt < 2; ++rt)
#pragma unroll
          for (int ct = 0; ct < 4; ++ct)
            acc_s[rt][ct] = __builtin_amdgcn_mfma_f32_16x16x32_bf16(af[rt], bk[ct], acc_s[rt][ct], 0, 0, 0);
      }
    }

    // ---- P = exp(S/sqrt(D)) -> bf16 -> LDS (swizzled [64][256]); per-lane l partials ----
#pragma unroll
    for (int rt = 0; rt < 2; ++rt)
#pragma unroll
      for (int ct = 0; ct < 4; ++ct)
#pragma unroll
        for (int g = 0; g < 4; ++g) {
          float p = exp2f(acc_s[rt][ct][g] * SCALE_LOG2E);
          acc_lp[rt * 4 + g] += p;
          int row = R * 32 + rt * 16 + l4 * 4 + g;
          int col = C * 64 + ct * 16 + l15;
          int off = row * 512 + ((((col >> 3) ^ (row & 7))) << 4) + ((col & 7) << 1);
          *(unsigned short*)(Pl + off) = f2bf(p);
        }

    // ---- PV: O[64x768] += P[64x256] @ V; 32x32x16 MFMA; 8 rounds of 32 keys ----
#pragma unroll 1
    for (int v = 0; v < 8; ++v) {
      __syncthreads();  // drains stage(v) (+P writes at v=0); prev compute done
      if (v + 1 < 8) stagePV(v + 1);
      const char* Vc = lds + ((v & 1) ^ 1) * 49152;
#pragma unroll
      for (int s = 0; s < 2; ++s) {
        const int kg = v * 4 + s * 2 + h;   // P col-group (8 cols each), 0..31
        s16x8 pa[2], vb[3];
#pragma unroll
        for (int rs = 0; rs < 2; ++rs) {
          int row = rs * 32 + l31;
          int pc = (kg & ~7) | ((kg & 7) ^ (row & 7));
          pa[rs] = *(const s16x8*)(Pl + row * 512 + (pc << 4));
        }
#pragma unroll
        for (int ct = 0; ct < 3; ++ct) {
          int vr = wv * 32 + ct * 256 + l31;
          int rp = vr >> 1;
          int p3 = (((vr & 1) << 2) | (s * 2 + h)) ^ (rp & 7);
          vb[ct] = *(const s16x8*)(Vc + rp * 128 + (p3 << 4));
        }
#pragma unroll
        for (int rs = 0; rs < 2; ++rs)
#pragma unroll
          for (int ct = 0; ct < 3; ++ct)
            acc_o[rs][ct] = __builtin_amdgcn_mfma_f32_32x32x16_bf16(pa[rs], vb[ct], acc_o[rs][ct], 0, 0, 0);
      }
    }
    __syncthreads();  // V/P consumed before next iter's staging / P rewrite
  }

  // ---- l reduction: butterfly over lane bits 0..3 (16 cols/group), combine quarters ----
#pragma unroll
  for (int i = 0; i < 8; ++i) {
    float v = acc_lp[i];
    v += __shfl_xor(v, 1); v += __shfl_xor(v, 2);
    v += __shfl_xor(v, 4); v += __shfl_xor(v, 8);
    acc_lp[i] = v;
  }
  if (l15 == 0) {
#pragma unroll
    for (int rt = 0; rt < 2; ++rt)
#pragma unroll
      for (int g = 0; g < 4; ++g)
        l_part[C * 64 + R * 32 + rt * 16 + l4 * 4 + g] = acc_lp[rt * 4 + g];
  }
  __syncthreads();

  // O epilogue: 32x32 C/D layout: col = l31 (+base), row = (reg&3)+8*(reg>>2)+4*h (+rs*32)
  if (!norm_out) {
    if (tid < 64)
      lout[(long)split * SEQ + qrow0 + tid] =
          l_part[tid] + l_part[64 + tid] + l_part[128 + tid] + l_part[192 + tid];
#pragma unroll
    for (int rs = 0; rs < 2; ++rs)
#pragma unroll
      for (int reg = 0; reg < 16; ++reg) {
        int row = rs * 32 + (reg & 3) + 8 * (reg >> 2) + 4 * h;
#pragma unroll
        for (int ct = 0; ct < 3; ++ct) {
          int col = wv * 32 + ct * 256 + l31;
          partp[(long)split * SEQ * DIM + (qrow0 + row) * DIM + col] = f2bf(acc_o[rs][ct][reg]);
        }
      }
  } else {
#pragma unroll
    for (int rs = 0; rs < 2; ++rs)
#pragma unroll
      for (int reg = 0; reg < 16; ++reg) {
        int row = rs * 32 + (reg & 3) + 8 * (reg >> 2) + 4 * h;
        float inv = 1.0f / (l_part[row] + l_part[64 + row] + l_part[128 + row] + l_part[192 + row]);
#pragma unroll
        for (int ct = 0; ct < 3; ++ct) {
          int col = wv * 32 + ct * 256 + l31;
          outf[(qrow0 + row) * DIM + col] = acc_o[rs][ct][reg] * inv;
        }
      }
  }
}

// ---------------- combine (G=2): out = (p0+p1)/(l0+l1), partials bf16 ----------------
__global__ void combine_kernel(const unsigned short* __restrict__ part,
                               const float* __restrict__ lsum,
                               float* __restrict__ out, int n4) {
  int i = blockIdx.x * blockDim.x + threadIdx.x;
  if (i >= n4) return;
  int row = (i * 4) / DIM;
  ushort4 p0 = ((const ushort4*)part)[i];
  ushort4 p1 = ((const ushort4*)(part + (long)SEQ * DIM))[i];
  float inv = 1.0f / (lsum[row] + lsum[SEQ + row]);
  float4 o;
  o.x = (bf2f(p0.x) + bf2f(p1.x)) * inv;
  o.y = (bf2f(p0.y) + bf2f(p1.y)) * inv;
  o.z = (bf2f(p0.z) + bf2f(p1.z)) * inv;
  o.w = (bf2f(p0.w) + bf2f(p1.w)) * inv;
  ((float4*)out)[i] = o;
}

// ---------------- host ----------------
extern "C" void kernel_launch(void* const* d_in, const int* in_sizes, int n_in,
                              void* d_out, int out_size, void* d_ws, size_t ws_size,
                              hipStream_t stream) {
  const float* x = (const float*)d_in[0];
  const float* wq = (const float*)d_in[1];
  const float* wk = (const float*)d_in[2];
  const float* wv = (const float*)d_in[3];
  float* out = (float*)d_out;
  char* ws = (char*)d_ws;

  const size_t o_xbf = 0;
  const size_t o_wq = o_xbf + (size_t)SEQ * DIM * 2;
  const size_t o_wk = o_wq + (size_t)DIM * DIM * 2;
  const size_t o_wv = o_wk + (size_t)DIM * DIM * 2;
  const size_t o_q = o_wv + (size_t)DIM * DIM * 2;
  const size_t o_k = o_q + (size_t)SEQ * DIM * 2;
  const size_t o_vt = o_k + (size_t)SEQ * DIM * 2;
  const size_t o_part = o_vt + (size_t)SEQ * DIM * 2;
  const size_t o_l = o_part + (size_t)2 * SEQ * DIM * 2;   // bf16 partials
  const size_t total_g2 = o_l + (size_t)2 * SEQ * 4;

  unsigned short* Xbf = (unsigned short*)(ws + o_xbf);
  unsigned short* Wqb = (unsigned short*)(ws + o_wq);
  unsigned short* Wkb = (unsigned short*)(ws + o_wk);
  unsigned short* Wvb = (unsigned short*)(ws + o_wv);
  unsigned short* Qb = (unsigned short*)(ws + o_q);
  unsigned short* Kb = (unsigned short*)(ws + o_k);
  unsigned short* Vtb = (unsigned short*)(ws + o_vt);
  unsigned short* part = (unsigned short*)(ws + o_part);
  float* lbuf = (float*)(ws + o_l);

  const int G = (ws_size >= total_g2) ? 2 : 1;

  cast_all_kernel<<<7872, 256, 0, stream>>>(x, wq, wk, wv, Xbf, Wqb, Wkb, Wvb);
  proj_kernel<<<dim3(64, 6, 3), 256, 0, stream>>>(Xbf, Wqb, Wkb, Wvb, Qb, Kb, Vtb);
  if (G == 2) {
    flash_kernel<<<dim3(128, 2), 512, 0, stream>>>(Qb, Kb, Vtb, part, nullptr, lbuf, SEQ / 2, 0);
    combine_kernel<<<6144, 256, 0, stream>>>(part, lbuf, out, SEQ * DIM / 4);
  } else {
    flash_kernel<<<dim3(128, 1), 512, 0, stream>>>(Qb, Kb, Vtb, nullptr, out, nullptr, SEQ, 1);
  }
}

// Round 4
// 316.385 us; speedup vs baseline: 2.4126x; 1.1569x over previous
//
#include <hip/hip_runtime.h>

#define SEQ 8192
#define DIM 768

typedef __attribute__((ext_vector_type(8))) short s16x8;   // 8 x bf16
typedef __attribute__((ext_vector_type(4))) float f32x4;

// RNE float -> bf16
__device__ __forceinline__ unsigned short f2bf(float f) {
  union { float f; unsigned u; } v; v.f = f;
  unsigned r = v.u + 0x7FFFu + ((v.u >> 16) & 1u);
  return (unsigned short)(r >> 16);
}

__device__ __forceinline__ float bf2f(unsigned short s) {
  union { unsigned u; float f; } v; v.u = ((unsigned)s) << 16;
  return v.f;
}

// async global->LDS 16B copy: lds dest = wave-uniform base + lane*16
__device__ __forceinline__ void gll16(const void* gsrc, void* ldst) {
  __builtin_amdgcn_global_load_lds(
      (__attribute__((address_space(1))) unsigned int*)gsrc,
      (__attribute__((address_space(3))) unsigned int*)ldst, 16, 0, 0);
}

// ---------------- fused cast kernel: x (6144 blocks) + wq/wk/wv (576 each) ----------------
#define XN4 (SEQ * DIM / 4)     // 1572864
#define WN4 (DIM * DIM / 4)     // 147456

__global__ void cast_all_kernel(const float* __restrict__ x, const float* __restrict__ wq,
                                const float* __restrict__ wk, const float* __restrict__ wv,
                                unsigned short* __restrict__ dx, unsigned short* __restrict__ dq,
                                unsigned short* __restrict__ dk, unsigned short* __restrict__ dv) {
  int i = blockIdx.x * blockDim.x + threadIdx.x;
  const float* s;
  unsigned short* d;
  int off;
  if (i < XN4) {
    s = x; d = dx; off = i;
  } else {
    int j = i - XN4;
    int wi = j / WN4;
    off = j - wi * WN4;
    s = (wi == 0) ? wq : ((wi == 1) ? wk : wv);
    d = (wi == 0) ? dq : ((wi == 1) ? dk : dv);
  }
  float4 v = ((const float4*)s)[off];
  ushort4 r; r.x = f2bf(v.x); r.y = f2bf(v.y); r.z = f2bf(v.z); r.w = f2bf(v.w);
  ((ushort4*)d)[off] = r;
}

// ---------------- projection GEMM: C[m][n] = sum_k X[m][k]*W[n][k] ----------------
// z==2 writes V in key-blocked layout: Vt_blk[key>>5][vr 768][key&31]
__global__ __launch_bounds__(256, 2)
void proj_kernel(const unsigned short* __restrict__ X,
                 const unsigned short* __restrict__ Wq,
                 const unsigned short* __restrict__ Wk,
                 const unsigned short* __restrict__ Wv,
                 unsigned short* __restrict__ Qb,
                 unsigned short* __restrict__ Kb,
                 unsigned short* __restrict__ Vtb) {
  __shared__ __align__(16) char lds[65536];
  const int tid = threadIdx.x;
  const int lane = tid & 63, wv = tid >> 6;
  const int l15 = lane & 15, l4 = lane >> 4;
  const int mt = blockIdx.x, nt = blockIdx.y, z = blockIdx.z;
  const unsigned short* W = (z == 0) ? Wq : ((z == 1) ? Wk : Wv);

  f32x4 acc[4][4];
#pragma unroll
  for (int i = 0; i < 4; ++i)
#pragma unroll
    for (int j = 0; j < 4; ++j) acc[i][j] = f32x4{0.f, 0.f, 0.f, 0.f};

  auto stage = [&](int kk) {
    char* At = lds + (kk & 1) * 32768;
    char* Bt = At + 16384;
    const int d0 = kk * 64;
#pragma unroll
    for (int i = 0; i < 4; ++i) {
      int s = i * 256 + tid;
      int row = s >> 3, c = (s & 7) ^ (row & 7);
      gll16(X + (long)(mt * 128 + row) * DIM + d0 + c * 8, At + i * 4096 + (wv << 10));
      gll16(W + (long)(nt * 128 + row) * DIM + d0 + c * 8, Bt + i * 4096 + (wv << 10));
    }
  };

  stage(0);
#pragma unroll 1
  for (int kk = 0; kk < 12; ++kk) {
    __syncthreads();
    if (kk + 1 < 12) stage(kk + 1);
    const char* At = lds + (kk & 1) * 32768;
    const char* Bt = At + 16384;
#pragma unroll
    for (int ks = 0; ks < 2; ++ks) {
      const int c = ks * 4 + l4;
      s16x8 a[4], b[4];
#pragma unroll
      for (int mi = 0; mi < 4; ++mi) {
        int row = (wv & 1) * 64 + mi * 16 + l15;
        a[mi] = *(const s16x8*)(At + row * 128 + ((c ^ (row & 7)) << 4));
      }
#pragma unroll
      for (int ni = 0; ni < 4; ++ni) {
        int row = (wv >> 1) * 64 + ni * 16 + l15;
        b[ni] = *(const s16x8*)(Bt + row * 128 + ((c ^ (row & 7)) << 4));
      }
#pragma unroll
      for (int mi = 0; mi < 4; ++mi)
#pragma unroll
        for (int ni = 0; ni < 4; ++ni)
          acc[mi][ni] = __builtin_amdgcn_mfma_f32_16x16x32_bf16(a[mi], b[ni], acc[mi][ni], 0, 0, 0);
    }
  }

#pragma unroll
  for (int mi = 0; mi < 4; ++mi)
#pragma unroll
    for (int ni = 0; ni < 4; ++ni) {
      int row0 = mt * 128 + (wv & 1) * 64 + mi * 16 + l4 * 4;
      int col = nt * 128 + (wv >> 1) * 64 + ni * 16 + l15;
      if (z == 2) {
        ushort4 r;
        r.x = f2bf(acc[mi][ni][0]); r.y = f2bf(acc[mi][ni][1]);
        r.z = f2bf(acc[mi][ni][2]); r.w = f2bf(acc[mi][ni][3]);
        // blocked: [row0>>5][col][row0&31]; keys row0..row0+3 stay in one 32-block
        *(ushort4*)(Vtb + (long)(row0 >> 5) * (DIM * 32) + col * 32 + (row0 & 31)) = r;
      } else {
        unsigned short* dst = (z == 0) ? Qb : Kb;
#pragma unroll
        for (int g = 0; g < 4; ++g)
          dst[(long)(row0 + g) * DIM + col] = f2bf(acc[mi][ni][g]);
      }
    }
}

// ---------------- flash attention (R0 skeleton; PV restructured: full-width V rounds) ----
// BM=64 q rows/block, BN=256 keys/iter, 8 waves, all 16x16x32 MFMA.
// QK phase: identical to the 293us kernel.
// PV phase: 8 rounds of 32 keys x all 768 vr (48KB stages from blocked Vt).
//   Per round: pa[4] read ONCE (no cc re-read) + 6 vb + 24 MFMA.
//   PV LDS reads 1152 -> 640 per CU-iter; read patterns stay 16-lane (2-way-free).
// LDS map: QK B0=[0..40960) B1=[40960..81920); V slotA chunks {0,8K,16K,24K,32K,80K},
//   slotB chunks {40K,48K,56K,64K,72K,88K} (8KB each; tails in [81920..98304));
//   P=[98304..131072); l_part aliases arena[0..1024) post-loop.
// Cross-phase prefetch: stagePV(0) at QK r=11 (reads B1; dest in B0+tailA);
//   next-iter stageQK(0) at PV v=7 (reads slotB; dest B0). Depth stays 1.
#define SCALE_LOG2E 0.05205878f  // (1/sqrt(768)) * log2(e)

__global__ __launch_bounds__(512, 2)
void flash_kernel(const unsigned short* __restrict__ Q,   // [8192][768] bf16
                  const unsigned short* __restrict__ K,   // [8192][768] bf16
                  const unsigned short* __restrict__ V,   // blocked Vt [256][768][32] bf16
                  unsigned short* __restrict__ partp,     // [G][8192][768] bf16 (G-split mode)
                  float* __restrict__ outf,               // [8192][768] fp32 (norm mode)
                  float* __restrict__ lout,               // [G][8192] (G-split mode)
                  int kv_len, int norm_out) {
  __shared__ __align__(16) char lds[131072];
  char* Pl = lds + 98304;
  float* l_part = (float*)lds;  // [4][64], used only after the main loop

  const int tid = threadIdx.x;
  const int lane = tid & 63, wv = tid >> 6;
  const int l15 = lane & 15, l4 = lane >> 4;
  const int qtile = blockIdx.x, split = blockIdx.y;
  const long kv0 = (long)split * kv_len;
  const long qrow0 = (long)qtile * 64;
  const int R = wv & 1;   // S row-half
  const int C = wv >> 1;  // S key-quarter

  f32x4 acc_o[4][6];
  float acc_lp[8];
#pragma unroll
  for (int i = 0; i < 4; ++i)
#pragma unroll
    for (int j = 0; j < 6; ++j) acc_o[i][j] = f32x4{0.f, 0.f, 0.f, 0.f};
#pragma unroll
  for (int i = 0; i < 8; ++i) acc_lp[i] = 0.f;

  const int niter = kv_len >> 8;

  // V chunk base: parity 0 -> {0..32K, 80K}, parity 1 -> {40K..72K, 88K}
  auto vchunk = [&](int par, int j) -> char* {
    int base = par ? ((j < 5) ? 40960 + j * 8192 : 90112)
                   : ((j < 5) ? j * 8192 : 81920);
    return lds + base;
  };

  auto stageQK = [&](int r, long kbase) {
    char* Qc = lds + (r & 1) * 40960;
    char* Kc = Qc + 8192;
    const int d0 = r * 64;
    {
      int s = tid;
      int row = s >> 3, c = (s & 7) ^ (row & 7);
      gll16(Q + (qrow0 + row) * DIM + d0 + c * 8, Qc + (wv << 10));
    }
#pragma unroll
    for (int i = 0; i < 4; ++i) {
      int s = i * 512 + tid;
      int row = s >> 3, c = (s & 7) ^ (row & 7);
      gll16(K + (kbase + row) * DIM + d0 + c * 8, Kc + i * 8192 + (wv << 10));
    }
  };

  // stage V block (kblk0+v): 48KB = 6 chunks of [128 vr][64B]; within a chunk,
  // data (vr,k4) lives at slot rp*8 + p3, rp=vr>>1, p3=(((vr&1)<<2)|k4)^(rp&7).
  // Linear LDS dest -> inverse-swizzle the global source (G21).
  auto stagePV = [&](int v, long kblk0) {
    const int par = v & 1;
    const long blkbase = (kblk0 + v) * (long)(DIM * 32);
    int s = wv * 64 + lane;          // slot within chunk (dest = base + lane*16)
    int rp = s >> 3, p3 = s & 7;
    int orig = p3 ^ (rp & 7);
    int vr_in = rp * 2 + (orig >> 2);
    int k4 = orig & 3;
#pragma unroll
    for (int i = 0; i < 6; ++i)
      gll16(V + blkbase + (long)(i * 128 + vr_in) * 32 + k4 * 8, vchunk(par, i) + (wv << 10));
  };

  stageQK(0, kv0);
#pragma unroll 1
  for (int it = 0; it < niter; ++it) {
    const long kb = kv0 + (long)it * 256;
    const long kblk0 = kb >> 5;

    // ---- QK: S[64x256], per-wave region [32 rows x 64 keys] = 2x4 16x16 tiles ----
    f32x4 acc_s[2][4];
#pragma unroll
    for (int a = 0; a < 2; ++a)
#pragma unroll
      for (int b = 0; b < 4; ++b) acc_s[a][b] = f32x4{0.f, 0.f, 0.f, 0.f};

#pragma unroll 1
    for (int r = 0; r < 12; ++r) {
      __syncthreads();  // drains stage(r); all waves done with prior compute
      if (r + 1 < 12) stageQK(r + 1, kb);
      else stagePV(0, kblk0);  // dest B0+tailA; r=11 reads B1 -> disjoint
      const char* Qc = lds + (r & 1) * 40960;
      const char* Kc = Qc + 8192;
#pragma unroll
      for (int ks = 0; ks < 2; ++ks) {
        const int c = ks * 4 + l4;
        s16x8 af[2], bk[4];
#pragma unroll
        for (int rt = 0; rt < 2; ++rt) {
          int row = R * 32 + rt * 16 + l15;
          af[rt] = *(const s16x8*)(Qc + row * 128 + ((c ^ (row & 7)) << 4));
        }
#pragma unroll
        for (int ct = 0; ct < 4; ++ct) {
          int kr = C * 64 + ct * 16 + l15;
          bk[ct] = *(const s16x8*)(Kc + kr * 128 + ((c ^ (kr & 7)) << 4));
        }
#pragma unroll
        for (int rt = 0; rt < 2; ++rt)
#pragma unroll
          for (int ct = 0; ct < 4; ++ct)
            acc_s[rt][ct] = __builtin_amdgcn_mfma_f32_16x16x32_bf16(af[rt], bk[ct], acc_s[rt][ct], 0, 0, 0);
      }
    }

    // ---- P = exp(S/sqrt(D)) -> bf16 -> LDS (swizzled [64][256]); per-lane l partials ----
#pragma unroll
    for (int rt = 0; rt < 2; ++rt)
#pragma unroll
      for (int ct = 0; ct < 4; ++ct)
#pragma unroll
        for (int g = 0; g < 4; ++g) {
          float p = exp2f(acc_s[rt][ct][g] * SCALE_LOG2E);
          acc_lp[rt * 4 + g] += p;
          int row = R * 32 + rt * 16 + l4 * 4 + g;
          int col = C * 64 + ct * 16 + l15;
          int off = row * 512 + ((((col >> 3) ^ (row & 7))) << 4) + ((col & 7) << 1);
          *(unsigned short*)(Pl + off) = f2bf(p);
        }

    // ---- PV: O[64x768] += P[64x256] @ V; 8 rounds of 32 keys x full 768 d ----
#pragma unroll 1
    for (int v = 0; v < 8; ++v) {
      __syncthreads();  // drains stage(v) (+P ds_writes at v=0); prev compute done
      if (v + 1 < 8) stagePV(v + 1, kblk0);
      else if (it + 1 < niter) stageQK(0, kb + 256);  // dest B0; v=7 reads slotB
      const int par = v & 1;
      s16x8 pa[4];
      const int ck = v * 4 + l4;
#pragma unroll
      for (int rs = 0; rs < 4; ++rs) {
        int row = rs * 16 + l15;
        int pc = (ck & ~7) | ((ck & 7) ^ (row & 7));
        pa[rs] = *(const s16x8*)(Pl + row * 512 + (pc << 4));
      }
      const int vr_l = wv * 16 + l15;          // vr & 127 (same for t=0,1)
      const int rp = vr_l >> 1;
      const int p3 = (((l15 & 1) << 2) | l4) ^ (rp & 7);
#pragma unroll
      for (int cc = 0; cc < 3; ++cc)
#pragma unroll
        for (int t = 0; t < 2; ++t) {
          const char* vcb = vchunk(par, cc * 2 + t);
          s16x8 vb = *(const s16x8*)(vcb + rp * 128 + (p3 << 4));
#pragma unroll
          for (int rs = 0; rs < 4; ++rs)
            acc_o[rs][cc * 2 + t] =
                __builtin_amdgcn_mfma_f32_16x16x32_bf16(pa[rs], vb, acc_o[rs][cc * 2 + t], 0, 0, 0);
        }
    }
  }

  // ---- l reduction: butterfly over lane bits 0..3 (16 cols/group), combine quarters ----
#pragma unroll
  for (int i = 0; i < 8; ++i) {
    float v = acc_lp[i];
    v += __shfl_xor(v, 1); v += __shfl_xor(v, 2);
    v += __shfl_xor(v, 4); v += __shfl_xor(v, 8);
    acc_lp[i] = v;
  }
  __syncthreads();  // all arena staging/reads done before l_part alias use
  if (l15 == 0) {
#pragma unroll
    for (int rt = 0; rt < 2; ++rt)
#pragma unroll
      for (int g = 0; g < 4; ++g)
        l_part[C * 64 + R * 32 + rt * 16 + l4 * 4 + g] = acc_lp[rt * 4 + g];
  }
  __syncthreads();

  if (!norm_out) {
    if (tid < 64)
      lout[(long)split * SEQ + qrow0 + tid] =
          l_part[tid] + l_part[64 + tid] + l_part[128 + tid] + l_part[192 + tid];
#pragma unroll
    for (int rt = 0; rt < 4; ++rt) {
      int row = rt * 16 + l4 * 4;
#pragma unroll
      for (int j = 0; j < 6; ++j) {
        int cc = j >> 1, t = j & 1;
        int col = (cc * 16 + wv + 8 * t) * 16 + l15;
#pragma unroll
        for (int g = 0; g < 4; ++g)
          partp[(long)split * SEQ * DIM + (qrow0 + row + g) * DIM + col] = f2bf(acc_o[rt][j][g]);
      }
    }
  } else {
    float linv[4][4];
#pragma unroll
    for (int rt = 0; rt < 4; ++rt)
#pragma unroll
      for (int g = 0; g < 4; ++g) {
        int row = rt * 16 + l4 * 4 + g;
        linv[rt][g] = 1.0f / (l_part[row] + l_part[64 + row] + l_part[128 + row] + l_part[192 + row]);
      }
#pragma unroll
    for (int rt = 0; rt < 4; ++rt) {
      int row = rt * 16 + l4 * 4;
#pragma unroll
      for (int j = 0; j < 6; ++j) {
        int cc = j >> 1, t = j & 1;
        int col = (cc * 16 + wv + 8 * t) * 16 + l15;
#pragma unroll
        for (int g = 0; g < 4; ++g)
          outf[(qrow0 + row + g) * DIM + col] = acc_o[rt][j][g] * linv[rt][g];
      }
    }
  }
}

// ---------------- combine (G=2): out = (p0+p1)/(l0+l1), partials bf16 ----------------
__global__ void combine_kernel(const unsigned short* __restrict__ part,
                               const float* __restrict__ lsum,
                               float* __restrict__ out, int n4) {
  int i = blockIdx.x * blockDim.x + threadIdx.x;
  if (i >= n4) return;
  int row = (i * 4) / DIM;
  ushort4 p0 = ((const ushort4*)part)[i];
  ushort4 p1 = ((const ushort4*)(part + (long)SEQ * DIM))[i];
  float inv = 1.0f / (lsum[row] + lsum[SEQ + row]);
  float4 o;
  o.x = (bf2f(p0.x) + bf2f(p1.x)) * inv;
  o.y = (bf2f(p0.y) + bf2f(p1.y)) * inv;
  o.z = (bf2f(p0.z) + bf2f(p1.z)) * inv;
  o.w = (bf2f(p0.w) + bf2f(p1.w)) * inv;
  ((float4*)out)[i] = o;
}

// ---------------- host ----------------
extern "C" void kernel_launch(void* const* d_in, const int* in_sizes, int n_in,
                              void* d_out, int out_size, void* d_ws, size_t ws_size,
                              hipStream_t stream) {
  const float* x = (const float*)d_in[0];
  const float* wq = (const float*)d_in[1];
  const float* wk = (const float*)d_in[2];
  const float* wv = (const float*)d_in[3];
  float* out = (float*)d_out;
  char* ws = (char*)d_ws;

  const size_t o_xbf = 0;
  const size_t o_wq = o_xbf + (size_t)SEQ * DIM * 2;
  const size_t o_wk = o_wq + (size_t)DIM * DIM * 2;
  const size_t o_wv = o_wk + (size_t)DIM * DIM * 2;
  const size_t o_q = o_wv + (size_t)DIM * DIM * 2;
  const size_t o_k = o_q + (size_t)SEQ * DIM * 2;
  const size_t o_vt = o_k + (size_t)SEQ * DIM * 2;
  const size_t o_part = o_vt + (size_t)SEQ * DIM * 2;
  const size_t o_l = o_part + (size_t)2 * SEQ * DIM * 2;   // bf16 partials
  const size_t total_g2 = o_l + (size_t)2 * SEQ * 4;

  unsigned short* Xbf = (unsigned short*)(ws + o_xbf);
  unsigned short* Wqb = (unsigned short*)(ws + o_wq);
  unsigned short* Wkb = (unsigned short*)(ws + o_wk);
  unsigned short* Wvb = (unsigned short*)(ws + o_wv);
  unsigned short* Qb = (unsigned short*)(ws + o_q);
  unsigned short* Kb = (unsigned short*)(ws + o_k);
  unsigned short* Vtb = (unsigned short*)(ws + o_vt);
  unsigned short* part = (unsigned short*)(ws + o_part);
  float* lbuf = (float*)(ws + o_l);

  const int G = (ws_size >= total_g2) ? 2 : 1;

  cast_all_kernel<<<7872, 256, 0, stream>>>(x, wq, wk, wv, Xbf, Wqb, Wkb, Wvb);
  proj_kernel<<<dim3(64, 6, 3), 256, 0, stream>>>(Xbf, Wqb, Wkb, Wvb, Qb, Kb, Vtb);
  if (G == 2) {
    flash_kernel<<<dim3(128, 2), 512, 0, stream>>>(Qb, Kb, Vtb, part, nullptr, lbuf, SEQ / 2, 0);
    combine_kernel<<<6144, 256, 0, stream>>>(part, lbuf, out, SEQ * DIM / 4);
  } else {
    flash_kernel<<<dim3(128, 1), 512, 0, stream>>>(Qb, Kb, Vtb, nullptr, out, nullptr, SEQ, 1);
  }
}